// Round 5
// baseline (3100.560 us; speedup 1.0000x reference)
//
#include <hip/hip_runtime.h>
#include <stdint.h>

// Problem constants
#define NB    16      // batch
#define H8    8       // heads
#define T512  512     // sequence
#define D1600 1600    // d_in = d_out = 25*64
#define EP    1664    // padded E (13 * 128)

typedef short s16x8 __attribute__((ext_vector_type(8)));
typedef float f32x4 __attribute__((ext_vector_type(4)));

__device__ __forceinline__ unsigned short f2bf(float f) {
  unsigned int u = __builtin_bit_cast(unsigned int, f);
  u += 0x7FFFu + ((u >> 16) & 1u);   // round-to-nearest-even
  return (unsigned short)(u >> 16);
}

__device__ __forceinline__ void gld_lds16(const void* g, void* l) {
  __builtin_amdgcn_global_load_lds(
      (const __attribute__((address_space(1))) unsigned int*)g,
      (__attribute__((address_space(3))) unsigned int*)l, 16, 0, 0);
}

// ---------------------------------------------------------------------------
// xf[(n*512+t)*1600 + c*25+v] = x[((n*64+c)*512+t)*25+v]   (fp32 -> bf16)
__global__ __launch_bounds__(256)
void conv_x_k(const float* __restrict__ x, unsigned short* __restrict__ xf) {
  size_t i = (size_t)blockIdx.x * 256 + threadIdx.x;
  if (i >= (size_t)NB * T512 * D1600) return;
  int d  = (int)(i % D1600);
  size_t nt = i / D1600;
  int t  = (int)(nt % T512);
  int n  = (int)(nt / T512);
  int c = d / 25, v = d % 25;
  xf[i] = f2bf(x[(((size_t)n * 64 + c) * 512 + t) * 25 + v]);
}

// ---------------------------------------------------------------------------
// Wt[b][e][d] = W_i[h][d][e]  (b = i*8+h), zero for e in [1600,1664)
__global__ __launch_bounds__(256)
void conv_w_k(const float* __restrict__ Wq, const float* __restrict__ Wk,
              const float* __restrict__ Wv, unsigned short* __restrict__ Wt) {
  __shared__ float tile[32][33];
  int b = blockIdx.z, i3 = b >> 3, h = b & 7;
  const float* W = (i3 == 0 ? Wq : i3 == 1 ? Wk : Wv) + (size_t)h * D1600 * D1600;
  unsigned short* Wo = Wt + (size_t)b * EP * D1600;
  int e0 = blockIdx.x * 32, d0 = blockIdx.y * 32;
  int tx = threadIdx.x & 31, ty = threadIdx.x >> 5;
#pragma unroll
  for (int j = 0; j < 4; ++j) {
    int d = d0 + ty + j * 8, e = e0 + tx;
    tile[ty + j * 8][tx] = (e < D1600) ? W[(size_t)d * D1600 + e] : 0.f;
  }
  __syncthreads();
#pragma unroll
  for (int j = 0; j < 4; ++j) {
    int e = e0 + ty + j * 8, d = d0 + tx;
    Wo[(size_t)e * D1600 + d] = f2bf(tile[tx][ty + j * 8]);
  }
}

// ---------------------------------------------------------------------------
// NT GEMM, m97 structure: C[m][n] = scale * sum_k A[m][k]*B[n][k] (+bias)
// MODE 0: proj   A=xf(8192x1600), B=Wt[b](1664x1600) -> Q/K/V bf16 [n][h][t][e]
// MODE 1: QK^T   A=Q[z](512x1664), B=K[z] -> S fp32 (x 1/40)
// MODE 2: PV     A=P[z](512x512),  B=Vt[z](1664x512) -> O fp32 (half-batch)
template <int MODE>
__global__ __launch_bounds__(256, 2)
void gemm_nt(const unsigned short* __restrict__ Ag,
             const unsigned short* __restrict__ Bg,
             float* __restrict__ Cf,
             unsigned short* __restrict__ Qo, unsigned short* __restrict__ Ko,
             unsigned short* __restrict__ Vo,
             const float* __restrict__ bq, const float* __restrict__ bk,
             const float* __restrict__ bv,
             int Klen, int lda, int ldb, float scale, int zbase) {
  constexpr int BM = 128, BN = 128, BK = 64;
  __shared__ unsigned short As[BM * BK];
  __shared__ unsigned short Bs[BN * BK];

  const int tid = threadIdx.x;
  const int wid = tid >> 6;
  const int lane = tid & 63;
  const int wr = wid >> 1, wc = wid & 1;
  const int m0 = blockIdx.y * BM;
  const int n0 = blockIdx.x * BN;
  const int z = zbase + blockIdx.z;

  const unsigned short* Ab;
  const unsigned short* Bb;
  if (MODE == 0)      { Ab = Ag;                            Bb = Bg + (size_t)z * EP * D1600; }
  else if (MODE == 1) { Ab = Ag + (size_t)z * T512 * EP;    Bb = Bg + (size_t)z * T512 * EP;  }
  else                { Ab = Ag + (size_t)z * T512 * T512;  Bb = Bg + (size_t)z * EP * T512;  }

  f32x4 acc[4][4] = {};

  const int srow = lane >> 3;        // 0..7
  const int scol = (lane & 7) * 8;   // element offset in k

  for (int k0 = 0; k0 < Klen; k0 += BK) {
#pragma unroll
    for (int i = 0; i < 4; ++i) {
      int row = i * 32 + wid * 8 + srow;
      gld_lds16(Ab + (size_t)(m0 + row) * lda + k0 + scol,
                &As[(size_t)(i * 32 + wid * 8) * BK]);
    }
#pragma unroll
    for (int i = 0; i < 4; ++i) {
      int row = i * 32 + wid * 8 + srow;
      gld_lds16(Bb + (size_t)(n0 + row) * ldb + k0 + scol,
                &Bs[(size_t)(i * 32 + wid * 8) * BK]);
    }
    __syncthreads();
#pragma unroll
    for (int ks = 0; ks < 2; ++ks) {
      s16x8 af[4], bfr[4];
#pragma unroll
      for (int mi = 0; mi < 4; ++mi)
        af[mi] = *(const s16x8*)&As[(wr * 64 + mi * 16 + (lane & 15)) * BK + ks * 32 + (lane >> 4) * 8];
#pragma unroll
      for (int ni = 0; ni < 4; ++ni)
        bfr[ni] = *(const s16x8*)&Bs[(wc * 64 + ni * 16 + (lane & 15)) * BK + ks * 32 + (lane >> 4) * 8];
#pragma unroll
      for (int mi = 0; mi < 4; ++mi)
#pragma unroll
        for (int ni = 0; ni < 4; ++ni)
          acc[mi][ni] = __builtin_amdgcn_mfma_f32_16x16x32_bf16(af[mi], bfr[ni], acc[mi][ni], 0, 0, 0);
    }
    __syncthreads();
  }

  const int crow = (lane >> 4) * 4;  // + r
  const int ccol = lane & 15;

  if (MODE == 0) {
    const int i3 = z >> 3, h = z & 7;
    unsigned short* Ob = (i3 == 0 ? Qo : i3 == 1 ? Ko : Vo);
    const float* bb = (i3 == 0 ? bq : i3 == 1 ? bk : bv) + (size_t)h * D1600;
#pragma unroll
    for (int mi = 0; mi < 4; ++mi) {
#pragma unroll
      for (int ni = 0; ni < 4; ++ni) {
        int col = n0 + wc * 64 + ni * 16 + ccol;
        float bias = (col < D1600) ? bb[col] : 0.f;
#pragma unroll
        for (int r = 0; r < 4; ++r) {
          int row = m0 + wr * 64 + mi * 16 + crow + r;
          int n = row >> 9, t = row & 511;
          Ob[((size_t)(n * 8 + h) * T512 + t) * EP + col] = f2bf(acc[mi][ni][r] + bias);
        }
      }
    }
  } else {
    // MODE 1: S indexed by absolute z; MODE 2: O indexed by blockIdx.z (half-buffer)
    float* Ob = (MODE == 1) ? Cf + (size_t)z * T512 * T512
                            : Cf + (size_t)blockIdx.z * T512 * EP;
    const int ldc = (MODE == 1) ? T512 : EP;
#pragma unroll
    for (int mi = 0; mi < 4; ++mi) {
#pragma unroll
      for (int ni = 0; ni < 4; ++ni) {
        int col = n0 + wc * 64 + ni * 16 + ccol;
#pragma unroll
        for (int r = 0; r < 4; ++r) {
          int row = m0 + wr * 64 + mi * 16 + crow + r;
          Ob[(size_t)row * ldc + col] = acc[mi][ni][r] * scale;
        }
      }
    }
  }
}

// ---------------------------------------------------------------------------
// Vt[z][e][s] = V[z][s][e]   (bf16 tile transpose)
__global__ __launch_bounds__(256)
void transpose_v_k(const unsigned short* __restrict__ V, unsigned short* __restrict__ Vt) {
  __shared__ unsigned short tile[32][33];
  int z = blockIdx.z;
  const unsigned short* Vz = V + (size_t)z * T512 * EP;
  unsigned short* Vo = Vt + (size_t)z * EP * T512;
  int e0 = blockIdx.x * 32, s0 = blockIdx.y * 32;
  int tx = threadIdx.x & 31, ty = threadIdx.x >> 5;
#pragma unroll
  for (int j = 0; j < 4; ++j)
    tile[ty + j * 8][tx] = Vz[(size_t)(s0 + ty + j * 8) * EP + e0 + tx];
  __syncthreads();
#pragma unroll
  for (int j = 0; j < 4; ++j)
    Vo[(size_t)(e0 + ty + j * 8) * T512 + s0 + tx] = tile[tx][ty + j * 8];
}

// ---------------------------------------------------------------------------
// Row softmax over 512 fp32 -> bf16 P. One 256-thread block per row.
__global__ __launch_bounds__(256)
void softmax_k(const float* __restrict__ S, unsigned short* __restrict__ P) {
  __shared__ float red[8];
  const int tid = threadIdx.x;
  const size_t row = blockIdx.x;
  const float* s = S + row * 512;
  float a = s[tid], b = s[tid + 256];
  float mx = fmaxf(a, b);
#pragma unroll
  for (int o = 32; o > 0; o >>= 1) mx = fmaxf(mx, __shfl_xor(mx, o));
  if ((tid & 63) == 0) red[tid >> 6] = mx;
  __syncthreads();
  mx = fmaxf(fmaxf(red[0], red[1]), fmaxf(red[2], red[3]));
  float ea = __expf(a - mx), eb = __expf(b - mx);
  float sum = ea + eb;
#pragma unroll
  for (int o = 32; o > 0; o >>= 1) sum += __shfl_xor(sum, o);
  if ((tid & 63) == 0) red[4 + (tid >> 6)] = sum;
  __syncthreads();
  float inv = 1.f / (red[4] + red[5] + red[6] + red[7]);
  unsigned short* p = P + row * 512;
  p[tid] = f2bf(ea * inv);
  p[tid + 256] = f2bf(eb * inv);
}

// ---------------------------------------------------------------------------
// out[n][g=c*8+h][t][v] = O[bz][t][e=v*64+c]; nh = zbase + bz.
__global__ __launch_bounds__(256)
void final_out_k(const float* __restrict__ O, float* __restrict__ out, int zbase) {
  __shared__ float sm[8 * 1600];
  const int nh = zbase + blockIdx.y, n = nh >> 3, h = nh & 7;
  const int t0 = blockIdx.x * 8;
  const float* o = O + ((size_t)blockIdx.y * T512 + t0) * EP;
  for (int idx = threadIdx.x; idx < 8 * 1600; idx += 256) {
    int tt = idx / 1600, e = idx % 1600;
    sm[tt * 1600 + (e & 63) * 25 + (e >> 6)] = o[(size_t)tt * EP + e];  // [t][c][v]
  }
  __syncthreads();
  for (int idx = threadIdx.x; idx < 64 * 200; idx += 256) {
    int c = idx / 200, r = idx % 200;       // r = tt*25 + v
    out[(((size_t)n * 512 + c * 8 + h) * T512 + t0) * 25 + r] = sm[(r / 25) * 1600 + c * 25 + (r % 25)];
  }
}

// ---------------------------------------------------------------------------
extern "C" void kernel_launch(void* const* d_in, const int* in_sizes, int n_in,
                              void* d_out, int out_size, void* d_ws, size_t ws_size,
                              hipStream_t stream) {
  const float* x  = (const float*)d_in[0];
  const float* Wq = (const float*)d_in[1];
  const float* bq = (const float*)d_in[2];
  const float* Wk = (const float*)d_in[3];
  const float* bk = (const float*)d_in[4];
  const float* Wv = (const float*)d_in[5];
  const float* bv = (const float*)d_in[6];
  float* out = (float*)d_out;
  char* ws = (char*)d_ws;

  // Workspace layout (bytes), lifetime-aliased. Peak need = 808,321,024 B.
  //   Wt    : [0, 127795200)           live: conv_w .. proj
  //   xf    : [127795200, 154009600)   live: conv_x .. proj
  //   Q     : [154009600, 372113408)   live: proj .. qkt
  //   K     : [372113408, 590217216)   live: proj .. qkt
  //   V     : [590217216, 808321024)   live: proj .. transpose
  //   S     : alias [0, 134217728)     live: qkt .. softmax   (over Wt+xf)
  //   Vt    : alias Q slot             live: transpose .. pv  (Q dead after qkt)
  //   P     : alias K slot (67.1MB)    live: softmax .. pv    (K dead after qkt)
  //   Ohalf : [439222272, 657326080)   live: pv-half .. final-half (over K-tail+V)
  const size_t NEED = 808321024ULL;
  if (ws_size < NEED) return;  // clean mismatch instead of OOB container crash

  unsigned short* Wt = (unsigned short*)(ws + 0ULL);
  unsigned short* xf = (unsigned short*)(ws + 127795200ULL);
  unsigned short* Q  = (unsigned short*)(ws + 154009600ULL);
  unsigned short* K  = (unsigned short*)(ws + 372113408ULL);
  unsigned short* V  = (unsigned short*)(ws + 590217216ULL);
  float*          S  = (float*)(ws + 0ULL);
  unsigned short* Vt = (unsigned short*)(ws + 154009600ULL);
  unsigned short* P  = (unsigned short*)(ws + 372113408ULL);
  float*          Oh = (float*)(ws + 439222272ULL);

  (void)in_sizes; (void)n_in; (void)out_size;

  conv_x_k<<<51200, 256, 0, stream>>>(x, xf);
  conv_w_k<<<dim3(52, 50, 24), 256, 0, stream>>>(Wq, Wk, Wv, Wt);
  // Projections: Q,K,V (bf16, [n*8+h][t][e], e-padded to 1664)
  gemm_nt<0><<<dim3(13, 64, 24), 256, 0, stream>>>(
      xf, Wt, nullptr, Q, K, V, bq, bk, bv, D1600, D1600, D1600, 1.0f, 0);
  // S = (Q K^T) / 40   (before transpose so Vt can alias Q)
  gemm_nt<1><<<dim3(4, 4, 128), 256, 0, stream>>>(
      Q, K, S, nullptr, nullptr, nullptr, nullptr, nullptr, nullptr,
      EP, EP, EP, 0.025f, 0);
  transpose_v_k<<<dim3(52, 16, 128), 256, 0, stream>>>(V, Vt);
  softmax_k<<<65536, 256, 0, stream>>>(S, P);
  // PV + output reshape in two z-halves (O half-buffer = 218 MB)
  for (int zb = 0; zb < 128; zb += 64) {
    gemm_nt<2><<<dim3(13, 4, 64), 256, 0, stream>>>(
        P, Vt, Oh, nullptr, nullptr, nullptr, nullptr, nullptr, nullptr,
        T512, T512, T512, 1.0f, zb);
    final_out_k<<<dim3(64, 64), 256, 0, stream>>>(Oh, out, zb);
  }
}

// Round 8
// 2532.226 us; speedup vs baseline: 1.2244x; 1.2244x over previous
//
#include <hip/hip_runtime.h>
#include <stdint.h>

// Problem constants
#define NB    16      // batch
#define H8    8       // heads
#define T512  512     // sequence
#define D1600 1600    // d_in = d_out = 25*64
#define EP    1664    // padded E (13 * 128)

typedef short s16x8 __attribute__((ext_vector_type(8)));
typedef float f32x4 __attribute__((ext_vector_type(4)));

__device__ __forceinline__ unsigned short f2bf(float f) {
  unsigned int u = __builtin_bit_cast(unsigned int, f);
  u += 0x7FFFu + ((u >> 16) & 1u);   // round-to-nearest-even
  return (unsigned short)(u >> 16);
}

__device__ __forceinline__ void gld_lds16(const void* g, void* l) {
  __builtin_amdgcn_global_load_lds(
      (const __attribute__((address_space(1))) unsigned int*)g,
      (__attribute__((address_space(3))) unsigned int*)l, 16, 0, 0);
}

// ---------------------------------------------------------------------------
// xf[(n*512+t)*1600 + c*25+v] = x[((n*64+c)*512+t)*25+v]   (fp32 -> bf16)
__global__ __launch_bounds__(256)
void conv_x_k(const float* __restrict__ x, unsigned short* __restrict__ xf) {
  size_t i = (size_t)blockIdx.x * 256 + threadIdx.x;
  if (i >= (size_t)NB * T512 * D1600) return;
  int d  = (int)(i % D1600);
  size_t nt = i / D1600;
  int t  = (int)(nt % T512);
  int n  = (int)(nt / T512);
  int c = d / 25, v = d % 25;
  xf[i] = f2bf(x[(((size_t)n * 64 + c) * 512 + t) * 25 + v]);
}

// ---------------------------------------------------------------------------
// Wt[b][e][d] = W_i[h][d][e]  (b = i*8+h), zero for e in [1600,1664)
__global__ __launch_bounds__(256)
void conv_w_k(const float* __restrict__ Wq, const float* __restrict__ Wk,
              const float* __restrict__ Wv, unsigned short* __restrict__ Wt) {
  __shared__ float tile[32][33];
  int b = blockIdx.z, i3 = b >> 3, h = b & 7;
  const float* W = (i3 == 0 ? Wq : i3 == 1 ? Wk : Wv) + (size_t)h * D1600 * D1600;
  unsigned short* Wo = Wt + (size_t)b * EP * D1600;
  int e0 = blockIdx.x * 32, d0 = blockIdx.y * 32;
  int tx = threadIdx.x & 31, ty = threadIdx.x >> 5;
#pragma unroll
  for (int j = 0; j < 4; ++j) {
    int d = d0 + ty + j * 8, e = e0 + tx;
    tile[ty + j * 8][tx] = (e < D1600) ? W[(size_t)d * D1600 + e] : 0.f;
  }
  __syncthreads();
#pragma unroll
  for (int j = 0; j < 4; ++j) {
    int e = e0 + ty + j * 8, d = d0 + tx;
    Wo[(size_t)e * D1600 + d] = f2bf(tile[tx][ty + j * 8]);
  }
}

// ---------------------------------------------------------------------------
// 256x256 pipelined projection GEMM (T1+T2+T3/T4+T5).
// C[m][n] = xf[m][k] * Wt[z][n][k] (+bias), m=8192, n=1792(7x256, guard<1664),
// K=1600 (25 tiles of BK=64). 512 threads = 8 waves (2M x 4N), per-wave 128x64.
// LDS 128KiB: A 2buf x [256][64] bf16, B same. XOR slot swizzle on both sides.
// Per K-tile: 4 phases {ds_read quadrant frags | stage 1 half | barrier |
// lgkmcnt(0) | setprio(1) 16 MFMA setprio(0) | barrier}; vmcnt(4) at phase 4.
// Stage schedule: ph1->A0(t+1), ph2->A1(t+1), ph3->B0(t+2), ph4->B1(t+2);
// each half staged only after its last reader phase + trailing barrier.
__global__ __launch_bounds__(512, 1)
void gemm256_proj(const unsigned short* __restrict__ Ag,   // xf 8192x1600
                  const unsigned short* __restrict__ Bg,   // Wt 24x1664x1600
                  unsigned short* __restrict__ Qo, unsigned short* __restrict__ Ko,
                  unsigned short* __restrict__ Vo,
                  const float* __restrict__ bq, const float* __restrict__ bk,
                  const float* __restrict__ bv) {
  __shared__ __align__(16) char lds[131072];
  const int tid  = threadIdx.x;
  const int lane = tid & 63;
  const int wid  = tid >> 6;
  const int wr   = wid >> 2;       // 0..1  (m-half)
  const int wc   = wid & 3;        // 0..3  (n-quarter)

  // T1: bijective XCD remap, 5376 wg = 8 XCD x 672; m fastest within chunk
  const int fid = blockIdx.x + 7 * (blockIdx.y + 32 * blockIdx.z);
  const int lid = (fid & 7) * 672 + (fid >> 3);
  const int m0 = (lid & 31) * 256;
  const int nz = lid >> 5;
  const int n0 = (nz % 7) * 256;
  const int z  = nz / 7;

  const unsigned short* Ab = Ag;
  const unsigned short* Bb = Bg + (size_t)z * EP * D1600;

  // staging constants: thread covers (row = base + tid/8, slot = tid%8);
  // source slot pre-swizzled so LDS[row][s] = G[row][s ^ (row&7)]
  const int srow = tid >> 3;                           // 0..63 (+64 for 2nd load)
  const int soff = (((tid & 7) ^ (srow & 7)) << 3);    // element offset of 16B slot

  auto stageA = [&](int b, int h, int kk) {
    const unsigned short* s0 = Ab + (size_t)(m0 + h * 128 + srow) * D1600 + kk * 64 + soff;
    char* d = lds + b * 32768 + h * 16384 + tid * 16;
    gld_lds16(s0, d);
    gld_lds16(s0 + (size_t)64 * D1600, d + 8192);
  };
  auto stageB = [&](int b, int h, int kk) {
    int r0 = n0 + h * 128 + srow;
    int r1 = r0 + 64;
    if (r0 > 1663) r0 = 1663;     // clamp: pad tiles re-read a valid row,
    if (r1 > 1663) r1 = 1663;     // results discarded by col<1664 write guard
    char* d = lds + 65536 + b * 32768 + h * 16384 + tid * 16;
    gld_lds16(Bb + (size_t)r0 * D1600 + kk * 64 + soff, d);
    gld_lds16(Bb + (size_t)r1 * D1600 + kk * 64 + soff, d + 8192);
  };

  // ds_read swizzled byte-slot for kh=0/1 (row&7 == lane&7 for all frag rows)
  const int arow = lane & 15;
  const int sw0 = (((lane >> 4)) ^ (lane & 7)) * 16;
  const int sw1 = ((4 + (lane >> 4)) ^ (lane & 7)) * 16;

  f32x4 acc[8][4] = {};
  s16x8 af[4][2], b0[2][2], b1[2][2];

  // prologue: tile0 all 4 halves + tile1 B halves; drain to 2 halves in flight
  stageA(0, 0, 0); stageA(0, 1, 0);
  stageB(0, 0, 0); stageB(0, 1, 0);
  stageB(1, 0, 1); stageB(1, 1, 1);
  asm volatile("s_waitcnt vmcnt(4)" ::: "memory");
  __builtin_amdgcn_s_barrier();

  for (int t = 0; t < 25; ++t) {
    const int cur = t & 1, nxt = cur ^ 1;
    const int ka = (t + 1 < 25) ? t + 1 : 24;
    const int kb = (t + 2 < 25) ? t + 2 : 24;
    const char* Abase = lds + cur * 32768 + wr * 16384;
    const char* Bbase = lds + 65536 + cur * 32768 + (wc >> 1) * 16384 + (wc & 1) * 8192;

    // ---- phase 1: frags A(mi0-3), B(ni0-1); stage A0(t+1); MFMA q00
#pragma unroll
    for (int m = 0; m < 4; ++m) {
      af[m][0] = *(const s16x8*)(Abase + (m * 16 + arow) * 128 + sw0);
      af[m][1] = *(const s16x8*)(Abase + (m * 16 + arow) * 128 + sw1);
    }
#pragma unroll
    for (int n = 0; n < 2; ++n) {
      b0[n][0] = *(const s16x8*)(Bbase + (n * 16 + arow) * 128 + sw0);
      b0[n][1] = *(const s16x8*)(Bbase + (n * 16 + arow) * 128 + sw1);
    }
    stageA(nxt, 0, ka);
    __builtin_amdgcn_s_barrier();
    asm volatile("s_waitcnt lgkmcnt(0)" ::: "memory");
    __builtin_amdgcn_sched_barrier(0);
    __builtin_amdgcn_s_setprio(1);
#pragma unroll
    for (int m = 0; m < 4; ++m)
#pragma unroll
      for (int n = 0; n < 2; ++n) {
        acc[m][n] = __builtin_amdgcn_mfma_f32_16x16x32_bf16(af[m][0], b0[n][0], acc[m][n], 0, 0, 0);
        acc[m][n] = __builtin_amdgcn_mfma_f32_16x16x32_bf16(af[m][1], b0[n][1], acc[m][n], 0, 0, 0);
      }
    __builtin_amdgcn_s_setprio(0);
    __builtin_amdgcn_s_barrier();

    // ---- phase 2: frags B(ni2-3); stage A1(t+1); MFMA q01
#pragma unroll
    for (int n = 0; n < 2; ++n) {
      b1[n][0] = *(const s16x8*)(Bbase + ((n + 2) * 16 + arow) * 128 + sw0);
      b1[n][1] = *(const s16x8*)(Bbase + ((n + 2) * 16 + arow) * 128 + sw1);
    }
    stageA(nxt, 1, ka);
    __builtin_amdgcn_s_barrier();
    asm volatile("s_waitcnt lgkmcnt(0)" ::: "memory");
    __builtin_amdgcn_sched_barrier(0);
    __builtin_amdgcn_s_setprio(1);
#pragma unroll
    for (int m = 0; m < 4; ++m)
#pragma unroll
      for (int n = 0; n < 2; ++n) {
        acc[m][n + 2] = __builtin_amdgcn_mfma_f32_16x16x32_bf16(af[m][0], b1[n][0], acc[m][n + 2], 0, 0, 0);
        acc[m][n + 2] = __builtin_amdgcn_mfma_f32_16x16x32_bf16(af[m][1], b1[n][1], acc[m][n + 2], 0, 0, 0);
      }
    __builtin_amdgcn_s_setprio(0);
    __builtin_amdgcn_s_barrier();

    // ---- phase 3: frags A(mi4-7); stage B0(t+2); MFMA q10 (b0 kept in regs)
#pragma unroll
    for (int m = 0; m < 4; ++m) {
      af[m][0] = *(const s16x8*)(Abase + ((m + 4) * 16 + arow) * 128 + sw0);
      af[m][1] = *(const s16x8*)(Abase + ((m + 4) * 16 + arow) * 128 + sw1);
    }
    stageB(cur, 0, kb);
    __builtin_amdgcn_s_barrier();
    asm volatile("s_waitcnt lgkmcnt(0)" ::: "memory");
    __builtin_amdgcn_sched_barrier(0);
    __builtin_amdgcn_s_setprio(1);
#pragma unroll
    for (int m = 0; m < 4; ++m)
#pragma unroll
      for (int n = 0; n < 2; ++n) {
        acc[m + 4][n] = __builtin_amdgcn_mfma_f32_16x16x32_bf16(af[m][0], b0[n][0], acc[m + 4][n], 0, 0, 0);
        acc[m + 4][n] = __builtin_amdgcn_mfma_f32_16x16x32_bf16(af[m][1], b0[n][1], acc[m + 4][n], 0, 0, 0);
      }
    __builtin_amdgcn_s_setprio(0);
    __builtin_amdgcn_s_barrier();

    // ---- phase 4: stage B1(t+2); vmcnt(4) -> tile t+1 fully landed; MFMA q11
    stageB(cur, 1, kb);
    asm volatile("s_waitcnt vmcnt(4)" ::: "memory");
    __builtin_amdgcn_s_barrier();
    __builtin_amdgcn_s_setprio(1);
#pragma unroll
    for (int m = 0; m < 4; ++m)
#pragma unroll
      for (int n = 0; n < 2; ++n) {
        acc[m + 4][n + 2] = __builtin_amdgcn_mfma_f32_16x16x32_bf16(af[m][0], b1[n][0], acc[m + 4][n + 2], 0, 0, 0);
        acc[m + 4][n + 2] = __builtin_amdgcn_mfma_f32_16x16x32_bf16(af[m][1], b1[n][1], acc[m + 4][n + 2], 0, 0, 0);
      }
    __builtin_amdgcn_s_setprio(0);
    __builtin_amdgcn_s_barrier();
  }

  asm volatile("s_waitcnt vmcnt(0)" ::: "memory");  // drain tail stages before endpgm
  __builtin_amdgcn_s_barrier();

  // epilogue: scatter to Q/K/V [n*8+h][t][e] bf16 (+bias), guard col<1664
  const int i3 = z >> 3, h = z & 7;
  unsigned short* Ob = (i3 == 0 ? Qo : i3 == 1 ? Ko : Vo);
  const float* bb = (i3 == 0 ? bq : i3 == 1 ? bk : bv) + (size_t)h * D1600;
#pragma unroll
  for (int mi = 0; mi < 8; ++mi)
#pragma unroll
    for (int ni = 0; ni < 4; ++ni) {
      const int col = n0 + wc * 64 + ni * 16 + (lane & 15);
      if (col < 1664) {
        const float bias = (col < D1600) ? bb[col] : 0.f;
#pragma unroll
        for (int r = 0; r < 4; ++r) {
          const int row = m0 + wr * 128 + mi * 16 + ((lane >> 4) << 2) + r;
          const int n = row >> 9, tt = row & 511;
          Ob[((size_t)(n * 8 + h) * T512 + tt) * EP + col] = f2bf(acc[mi][ni][r] + bias);
        }
      }
    }
}

// ---------------------------------------------------------------------------
// NT GEMM, m97 structure (unchanged, known-good):
// MODE 1: QK^T   A=Q[z](512x1664), B=K[z] -> S fp32 (x 1/40)
// MODE 2: PV     A=P[z](512x512),  B=Vt[z](1664x512) -> O fp32 (half-batch)
template <int MODE>
__global__ __launch_bounds__(256, 2)
void gemm_nt(const unsigned short* __restrict__ Ag,
             const unsigned short* __restrict__ Bg,
             float* __restrict__ Cf,
             int Klen, int lda, int ldb, float scale, int zbase) {
  constexpr int BM = 128, BN = 128, BK = 64;
  __shared__ unsigned short As[BM * BK];
  __shared__ unsigned short Bs[BN * BK];

  const int tid = threadIdx.x;
  const int wid = tid >> 6;
  const int lane = tid & 63;
  const int wr = wid >> 1, wc = wid & 1;
  const int m0 = blockIdx.y * BM;
  const int n0 = blockIdx.x * BN;
  const int z = zbase + blockIdx.z;

  const unsigned short* Ab;
  const unsigned short* Bb;
  if (MODE == 1) { Ab = Ag + (size_t)z * T512 * EP;   Bb = Bg + (size_t)z * T512 * EP; }
  else           { Ab = Ag + (size_t)z * T512 * T512; Bb = Bg + (size_t)z * EP * T512; }

  f32x4 acc[4][4] = {};

  const int srow = lane >> 3;
  const int scol = (lane & 7) * 8;

  for (int k0 = 0; k0 < Klen; k0 += BK) {
#pragma unroll
    for (int i = 0; i < 4; ++i) {
      int row = i * 32 + wid * 8 + srow;
      gld_lds16(Ab + (size_t)(m0 + row) * lda + k0 + scol,
                &As[(size_t)(i * 32 + wid * 8) * BK]);
    }
#pragma unroll
    for (int i = 0; i < 4; ++i) {
      int row = i * 32 + wid * 8 + srow;
      gld_lds16(Bb + (size_t)(n0 + row) * ldb + k0 + scol,
                &Bs[(size_t)(i * 32 + wid * 8) * BK]);
    }
    __syncthreads();
#pragma unroll
    for (int ks = 0; ks < 2; ++ks) {
      s16x8 af[4], bfr[4];
#pragma unroll
      for (int mi = 0; mi < 4; ++mi)
        af[mi] = *(const s16x8*)&As[(wr * 64 + mi * 16 + (lane & 15)) * BK + ks * 32 + (lane >> 4) * 8];
#pragma unroll
      for (int ni = 0; ni < 4; ++ni)
        bfr[ni] = *(const s16x8*)&Bs[(wc * 64 + ni * 16 + (lane & 15)) * BK + ks * 32 + (lane >> 4) * 8];
#pragma unroll
      for (int mi = 0; mi < 4; ++mi)
#pragma unroll
        for (int ni = 0; ni < 4; ++ni)
          acc[mi][ni] = __builtin_amdgcn_mfma_f32_16x16x32_bf16(af[mi], bfr[ni], acc[mi][ni], 0, 0, 0);
    }
    __syncthreads();
  }

  const int crow = (lane >> 4) * 4;
  const int ccol = lane & 15;
  float* Ob = (MODE == 1) ? Cf + (size_t)z * T512 * T512
                          : Cf + (size_t)blockIdx.z * T512 * EP;
  const int ldc = (MODE == 1) ? T512 : EP;
#pragma unroll
  for (int mi = 0; mi < 4; ++mi)
#pragma unroll
    for (int ni = 0; ni < 4; ++ni) {
      int col = n0 + wc * 64 + ni * 16 + ccol;
#pragma unroll
      for (int r = 0; r < 4; ++r) {
        int row = m0 + wr * 64 + mi * 16 + crow + r;
        Ob[(size_t)row * ldc + col] = acc[mi][ni][r] * scale;
      }
    }
}

// ---------------------------------------------------------------------------
// Vt[z][e][s] = V[z][s][e]   (bf16 tile transpose)
__global__ __launch_bounds__(256)
void transpose_v_k(const unsigned short* __restrict__ V, unsigned short* __restrict__ Vt) {
  __shared__ unsigned short tile[32][33];
  int z = blockIdx.z;
  const unsigned short* Vz = V + (size_t)z * T512 * EP;
  unsigned short* Vo = Vt + (size_t)z * EP * T512;
  int e0 = blockIdx.x * 32, s0 = blockIdx.y * 32;
  int tx = threadIdx.x & 31, ty = threadIdx.x >> 5;
#pragma unroll
  for (int j = 0; j < 4; ++j)
    tile[ty + j * 8][tx] = Vz[(size_t)(s0 + ty + j * 8) * EP + e0 + tx];
  __syncthreads();
#pragma unroll
  for (int j = 0; j < 4; ++j)
    Vo[(size_t)(e0 + ty + j * 8) * T512 + s0 + tx] = tile[tx][ty + j * 8];
}

// ---------------------------------------------------------------------------
// Row softmax over 512 fp32 -> bf16 P. One 256-thread block per row.
__global__ __launch_bounds__(256)
void softmax_k(const float* __restrict__ S, unsigned short* __restrict__ P) {
  __shared__ float red[8];
  const int tid = threadIdx.x;
  const size_t row = blockIdx.x;
  const float* s = S + row * 512;
  float a = s[tid], b = s[tid + 256];
  float mx = fmaxf(a, b);
#pragma unroll
  for (int o = 32; o > 0; o >>= 1) mx = fmaxf(mx, __shfl_xor(mx, o));
  if ((tid & 63) == 0) red[tid >> 6] = mx;
  __syncthreads();
  mx = fmaxf(fmaxf(red[0], red[1]), fmaxf(red[2], red[3]));
  float ea = __expf(a - mx), eb = __expf(b - mx);
  float sum = ea + eb;
#pragma unroll
  for (int o = 32; o > 0; o >>= 1) sum += __shfl_xor(sum, o);
  if ((tid & 63) == 0) red[4 + (tid >> 6)] = sum;
  __syncthreads();
  float inv = 1.f / (red[4] + red[5] + red[6] + red[7]);
  unsigned short* p = P + row * 512;
  p[tid] = f2bf(ea * inv);
  p[tid + 256] = f2bf(eb * inv);
}

// ---------------------------------------------------------------------------
// out[n][g=c*8+h][t][v] = O[bz][t][e=v*64+c]; nh = zbase + bz.
__global__ __launch_bounds__(256)
void final_out_k(const float* __restrict__ O, float* __restrict__ out, int zbase) {
  __shared__ float sm[8 * 1600];
  const int nh = zbase + blockIdx.y, n = nh >> 3, h = nh & 7;
  const int t0 = blockIdx.x * 8;
  const float* o = O + ((size_t)blockIdx.y * T512 + t0) * EP;
  for (int idx = threadIdx.x; idx < 8 * 1600; idx += 256) {
    int tt = idx / 1600, e = idx % 1600;
    sm[tt * 1600 + (e & 63) * 25 + (e >> 6)] = o[(size_t)tt * EP + e];  // [t][c][v]
  }
  __syncthreads();
  for (int idx = threadIdx.x; idx < 64 * 200; idx += 256) {
    int c = idx / 200, r = idx % 200;       // r = tt*25 + v
    out[(((size_t)n * 512 + c * 8 + h) * T512 + t0) * 25 + r] = sm[(r / 25) * 1600 + c * 25 + (r % 25)];
  }
}

// ---------------------------------------------------------------------------
extern "C" void kernel_launch(void* const* d_in, const int* in_sizes, int n_in,
                              void* d_out, int out_size, void* d_ws, size_t ws_size,
                              hipStream_t stream) {
  const float* x  = (const float*)d_in[0];
  const float* Wq = (const float*)d_in[1];
  const float* bq = (const float*)d_in[2];
  const float* Wk = (const float*)d_in[3];
  const float* bk = (const float*)d_in[4];
  const float* Wv = (const float*)d_in[5];
  const float* bv = (const float*)d_in[6];
  float* out = (float*)d_out;
  char* ws = (char*)d_ws;

  // Workspace layout (bytes), lifetime-aliased. Peak need = 808,321,024 B.
  const size_t NEED = 808321024ULL;
  if (ws_size < NEED) return;

  unsigned short* Wt = (unsigned short*)(ws + 0ULL);
  unsigned short* xf = (unsigned short*)(ws + 127795200ULL);
  unsigned short* Q  = (unsigned short*)(ws + 154009600ULL);
  unsigned short* K  = (unsigned short*)(ws + 372113408ULL);
  unsigned short* V  = (unsigned short*)(ws + 590217216ULL);
  float*          S  = (float*)(ws + 0ULL);
  unsigned short* Vt = (unsigned short*)(ws + 154009600ULL);
  unsigned short* P  = (unsigned short*)(ws + 372113408ULL);
  float*          Oh = (float*)(ws + 439222272ULL);

  (void)in_sizes; (void)n_in; (void)out_size;

  conv_x_k<<<51200, 256, 0, stream>>>(x, xf);
  conv_w_k<<<dim3(52, 50, 24), 256, 0, stream>>>(Wq, Wk, Wv, Wt);
  // Projections: 256x256 pipelined GEMM, grid 7x32x24 = 5376 wg (bijective /8)
  gemm256_proj<<<dim3(7, 32, 24), 512, 0, stream>>>(xf, Wt, Q, K, V, bq, bk, bv);
  // S = (Q K^T) / 40   (before transpose so Vt can alias Q)
  gemm_nt<1><<<dim3(4, 4, 128), 256, 0, stream>>>(Q, K, S, EP, EP, EP, 0.025f, 0);
  transpose_v_k<<<dim3(52, 16, 128), 256, 0, stream>>>(V, Vt);
  softmax_k<<<65536, 256, 0, stream>>>(S, P);
  // PV + output reshape in two z-halves (O half-buffer = 218 MB)
  for (int zb = 0; zb < 128; zb += 64) {
    gemm_nt<2><<<dim3(13, 4, 64), 256, 0, stream>>>(P, Vt, Oh, T512, T512, T512, 1.0f, zb);
    final_out_k<<<dim3(64, 64), 256, 0, stream>>>(Oh, out, zb);
  }
}